// Round 3
// baseline (28.947 us; speedup 1.0000x reference)
//
#include <hip/hip_runtime.h>
#include <stdint.h>

#define SLEN   4096
#define BATCH  4
#define DIM    64
#define HPROJ  16
#define PREFIX 6
#define KMAX   64

#define KLIST_CAP 4096
#define PAIR_CAP  4096

// ---------------- K1: per-token hash/signature + inserted flag + out init ----------------
// 8 threads per token (2 LSH projections each), shuffle-reduced.
__global__ void __launch_bounds__(256) k_phase1(
    const float* __restrict__ qup, const float* __restrict__ kup,
    const float* __restrict__ W,
    unsigned char* __restrict__ qh, unsigned char* __restrict__ kh,
    unsigned long long* __restrict__ qsig, unsigned long long* __restrict__ ksig,
    unsigned char* __restrict__ inserted,
    int* __restrict__ out)
{
    __shared__ float Ws[DIM * HPROJ];
    for (int i = threadIdx.x; i < DIM * HPROJ; i += 256) Ws[i] = W[i];
    __syncthreads();

    int gid = blockIdx.x * 256 + threadIdx.x;          // 0 .. 262143

    // fold the -1 output init into this kernel (4 ints per thread, 4 MB total)
    for (int o = gid; o < BATCH * SLEN * KMAX; o += 2 * BATCH * SLEN * 8)
        out[o] = -1;

    int token  = gid >> 3;                             // 0 .. 32767
    int hg     = gid & 7;                              // projection group
    int tensor = token >> 14;                          // 0 = query, 1 = key  (B*S = 16384)
    int rem    = token & (BATCH * SLEN - 1);
    int b      = rem >> 12;
    int s      = rem & (SLEN - 1);

    const float* x = (tensor ? kup : qup) + (size_t)rem * DIM;

    float4 xv[DIM / 4];
#pragma unroll
    for (int dv = 0; dv < DIM / 4; ++dv)
        xv[dv] = ((const float4*)x)[dv];

    int h0 = hg * 2;
    float p0 = 0.0f, p1 = 0.0f;
#pragma unroll
    for (int dv = 0; dv < DIM / 4; ++dv) {
        float4 v = xv[dv];
        int d = dv * 4;
        p0 = fmaf(v.x, Ws[(d + 0) * HPROJ + h0], p0);
        p0 = fmaf(v.y, Ws[(d + 1) * HPROJ + h0], p0);
        p0 = fmaf(v.z, Ws[(d + 2) * HPROJ + h0], p0);
        p0 = fmaf(v.w, Ws[(d + 3) * HPROJ + h0], p0);
        p1 = fmaf(v.x, Ws[(d + 0) * HPROJ + h0 + 1], p1);
        p1 = fmaf(v.y, Ws[(d + 1) * HPROJ + h0 + 1], p1);
        p1 = fmaf(v.z, Ws[(d + 2) * HPROJ + h0 + 1], p1);
        p1 = fmaf(v.w, Ws[(d + 3) * HPROJ + h0 + 1], p1);
    }
    // floor(p/4): /4 exact in fp32
    int acc = (int)floorf(p0 * 0.25f) + (int)floorf(p1 * 0.25f);
    acc += __shfl_xor(acc, 1);
    acc += __shfl_xor(acc, 2);
    acc += __shfl_xor(acc, 4);

    if (hg == 0) {
        unsigned char hash = (unsigned char)(acc & 63);   // Python mod 64
        if (!tensor) qh[rem] = hash; else kh[rem] = hash;

        if (b == BATCH - 1) {
            unsigned long long bits = 0ull;
#pragma unroll
            for (int dv = 0; dv < DIM / 4; ++dv) {
                float4 v = xv[dv];
                int d = dv * 4;
                if (v.x > 0.0f) bits |= (1ull << (d + 0));
                if (v.y > 0.0f) bits |= (1ull << (d + 1));
                if (v.z > 0.0f) bits |= (1ull << (d + 2));
                if (v.w > 0.0f) bits |= (1ull << (d + 3));
            }
            if (!tensor) {
                qsig[s] = bits;
            } else {
                ksig[s] = bits;
                // Wu-Manber filter: sign-prefix match q[0,s,:6] vs k[0,s,:6].
                // Single writer per s -> plain store, no init dispatch needed.
                const float* q0 = qup + (size_t)s * DIM;
                const float* k0 = kup + (size_t)s * DIM;
                bool ins = true;
#pragma unroll
                for (int j = 0; j < PREFIX; ++j)
                    ins &= ((q0[j] > 0.0f) == (k0[j] > 0.0f));
                inserted[s] = (unsigned char)ins;
            }
        }
    }
}

// ---------------- K2: compact inserted keys, probe, exact top-k, emit ----------------
__device__ inline float dot64(const float* a, const float* b)
{
    float s = 0.0f;
#pragma unroll
    for (int d = 0; d < DIM; ++d) s = fmaf(a[d], b[d], s);
    return s;
}

__global__ void __launch_bounds__(1024) k_match(
    const float* __restrict__ qup, const float* __restrict__ kup,
    const unsigned long long* __restrict__ qsig,
    const unsigned long long* __restrict__ ksig,
    const unsigned char* __restrict__ qh, const unsigned char* __restrict__ kh,
    const unsigned char* __restrict__ inserted,
    int* __restrict__ out)
{
    __shared__ int klist[KLIST_CAP];
    __shared__ unsigned long long ksigs[KLIST_CAP];
    __shared__ unsigned int pairs[PAIR_CAP];
    __shared__ int nk, np;

    int tid = threadIdx.x;
    if (tid == 0) { nk = 0; np = 0; }
    __syncthreads();

    // compact the inserted keys (expected ~S/64 = 64 of them)
    for (int k = tid; k < SLEN; k += 1024) {
        if (inserted[k]) {
            int p = atomicAdd(&nk, 1);
            if (p < KLIST_CAP) { klist[p] = k; ksigs[p] = ksig[k]; }
        }
    }
    __syncthreads();
    int m = nk < KLIST_CAP ? nk : KLIST_CAP;

    // probe: each thread owns 4 q rows; exact 64-bit sig match, then LSH per batch
    for (int q = tid; q < SLEN; q += 1024) {
        unsigned long long sv = qsig[q];
        for (int i = 0; i < m; ++i) {
            if (ksigs[i] == sv) {
                int k = klist[i];
                for (int b = 0; b < BATCH; ++b) {
                    if (qh[b * SLEN + q] == kh[b * SLEN + k]) {
                        int p = atomicAdd(&np, 1);
                        if (p < PAIR_CAP)
                            pairs[p] = ((unsigned)b << 24) | ((unsigned)q << 12) | (unsigned)k;
                    }
                }
            }
        }
    }
    __syncthreads();
    int n = np < PAIR_CAP ? np : PAIR_CAP;

    // exact top-k: rank among pairs sharing (b,q); reproduces lax.top_k order
    for (int i = tid; i < n; i += 1024) {
        unsigned u = pairs[i];
        int b = u >> 24, q = (u >> 12) & 4095, k = u & 4095;
        const float* qr = qup + ((size_t)(b * SLEN + q)) * DIM;
        float si = dot64(qr, kup + ((size_t)(b * SLEN + k)) * DIM);
        int rank = 0;
        for (int j = 0; j < n; ++j) {
            unsigned v = pairs[j];
            if ((v >> 12) == (u >> 12)) {                 // same (b, q)
                int kj = v & 4095;
                float sj = dot64(qr, kup + ((size_t)(b * SLEN + kj)) * DIM);
                rank += (sj > si) || (sj == si && kj < k);
            }
        }
        if (rank < KMAX)
            out[((size_t)(b * SLEN + q)) * KMAX + rank] = k;
    }
}

extern "C" void kernel_launch(void* const* d_in, const int* in_sizes, int n_in,
                              void* d_out, int out_size, void* d_ws, size_t ws_size,
                              hipStream_t stream)
{
    const float* qup = (const float*)d_in[0];
    const float* kup = (const float*)d_in[1];
    const float* W   = (const float*)d_in[2];
    int* out = (int*)d_out;

    char* w = (char*)d_ws;
    unsigned long long* qsig = (unsigned long long*)(w);             // 32 KB
    unsigned long long* ksig = (unsigned long long*)(w + 32768);     // 32 KB
    unsigned char* qh   = (unsigned char*)(w + 65536);               // 16 KB
    unsigned char* kh   = (unsigned char*)(w + 81920);               // 16 KB
    unsigned char* ins  = (unsigned char*)(w + 98304);               // 4 KB

    k_phase1<<<(2 * BATCH * SLEN * 8) / 256, 256, 0, stream>>>(
        qup, kup, W, qh, kh, qsig, ksig, ins, out);
    k_match<<<1, 1024, 0, stream>>>(qup, kup, qsig, ksig, qh, kh, ins, out);
}

// Round 4
// 24.092 us; speedup vs baseline: 1.2015x; 1.2015x over previous
//
#include <hip/hip_runtime.h>
#include <stdint.h>

#define SLEN   4096
#define BATCH  4
#define DIM    64
#define HPROJ  16
#define PREFIX 6
#define KMAX   64

#define KL_CAP 4096      // exact upper bound on inserted keys
#define PB_CAP 2048      // per-block pair cap (expected ~0 pairs)

// ---------------- K1: per-token hash/signature + inserted flag + out init ----------------
// 8 threads per token (2 LSH projections each), shuffle-reduced. (validated R1-R3)
__global__ void __launch_bounds__(256) k_phase1(
    const float* __restrict__ qup, const float* __restrict__ kup,
    const float* __restrict__ W,
    unsigned char* __restrict__ qh, unsigned char* __restrict__ kh,
    unsigned long long* __restrict__ qsig, unsigned long long* __restrict__ ksig,
    unsigned char* __restrict__ inserted,
    int* __restrict__ out)
{
    __shared__ float Ws[DIM * HPROJ];
    for (int i = threadIdx.x; i < DIM * HPROJ; i += 256) Ws[i] = W[i];
    __syncthreads();

    int gid = blockIdx.x * 256 + threadIdx.x;          // 0 .. 262143

    // fold the -1 output init into this kernel (4 ints per thread, 4 MB total)
    for (int o = gid; o < BATCH * SLEN * KMAX; o += 2 * BATCH * SLEN * 8)
        out[o] = -1;

    int token  = gid >> 3;                             // 0 .. 32767
    int hg     = gid & 7;                              // projection group
    int tensor = token >> 14;                          // 0 = query, 1 = key  (B*S = 16384)
    int rem    = token & (BATCH * SLEN - 1);
    int b      = rem >> 12;
    int s      = rem & (SLEN - 1);

    const float* x = (tensor ? kup : qup) + (size_t)rem * DIM;

    float4 xv[DIM / 4];
#pragma unroll
    for (int dv = 0; dv < DIM / 4; ++dv)
        xv[dv] = ((const float4*)x)[dv];

    int h0 = hg * 2;
    float p0 = 0.0f, p1 = 0.0f;
#pragma unroll
    for (int dv = 0; dv < DIM / 4; ++dv) {
        float4 v = xv[dv];
        int d = dv * 4;
        p0 = fmaf(v.x, Ws[(d + 0) * HPROJ + h0], p0);
        p0 = fmaf(v.y, Ws[(d + 1) * HPROJ + h0], p0);
        p0 = fmaf(v.z, Ws[(d + 2) * HPROJ + h0], p0);
        p0 = fmaf(v.w, Ws[(d + 3) * HPROJ + h0], p0);
        p1 = fmaf(v.x, Ws[(d + 0) * HPROJ + h0 + 1], p1);
        p1 = fmaf(v.y, Ws[(d + 1) * HPROJ + h0 + 1], p1);
        p1 = fmaf(v.z, Ws[(d + 2) * HPROJ + h0 + 1], p1);
        p1 = fmaf(v.w, Ws[(d + 3) * HPROJ + h0 + 1], p1);
    }
    // floor(p/4): /4 exact in fp32
    int acc = (int)floorf(p0 * 0.25f) + (int)floorf(p1 * 0.25f);
    acc += __shfl_xor(acc, 1);
    acc += __shfl_xor(acc, 2);
    acc += __shfl_xor(acc, 4);

    if (hg == 0) {
        unsigned char hash = (unsigned char)(acc & 63);   // Python mod 64
        if (!tensor) qh[rem] = hash; else kh[rem] = hash;

        if (b == BATCH - 1) {
            unsigned long long bits = 0ull;
#pragma unroll
            for (int dv = 0; dv < DIM / 4; ++dv) {
                float4 v = xv[dv];
                int d = dv * 4;
                if (v.x > 0.0f) bits |= (1ull << (d + 0));
                if (v.y > 0.0f) bits |= (1ull << (d + 1));
                if (v.z > 0.0f) bits |= (1ull << (d + 2));
                if (v.w > 0.0f) bits |= (1ull << (d + 3));
            }
            if (!tensor) {
                qsig[s] = bits;
            } else {
                ksig[s] = bits;
                // Wu-Manber filter: sign-prefix match q[0,s,:6] vs k[0,s,:6].
                const float* q0 = qup + (size_t)s * DIM;
                const float* k0 = kup + (size_t)s * DIM;
                bool ins = true;
#pragma unroll
                for (int j = 0; j < PREFIX; ++j)
                    ins &= ((q0[j] > 0.0f) == (k0[j] > 0.0f));
                inserted[s] = (unsigned char)ins;
            }
        }
    }
}

// ---------------- K2: per-block compact + probe + local exact top-k ----------------
// 16 blocks x 256 threads; thread owns q = blockIdx*256 + tid. All pairs for a
// given q are produced by its owning thread => ranking is block-local.
__device__ inline float dot64(const float* a, const float* b)
{
    float s = 0.0f;
#pragma unroll
    for (int d = 0; d < DIM; ++d) s = fmaf(a[d], b[d], s);
    return s;
}

__global__ void __launch_bounds__(256) k_match(
    const float* __restrict__ qup, const float* __restrict__ kup,
    const unsigned long long* __restrict__ qsig,
    const unsigned long long* __restrict__ ksig,
    const unsigned char* __restrict__ qh, const unsigned char* __restrict__ kh,
    const unsigned char* __restrict__ inserted,
    int* __restrict__ out)
{
    __shared__ unsigned long long ksigs[KL_CAP];
    __shared__ unsigned short     klist[KL_CAP];
    __shared__ unsigned int       pairs[PB_CAP];
    __shared__ int nk, np;

    int tid = threadIdx.x;
    if (tid == 0) { nk = 0; np = 0; }
    __syncthreads();

    // compact inserted keys into LDS (each k appears once -> nk <= 4096, no overflow)
    for (int k = tid; k < SLEN; k += 256) {
        if (inserted[k]) {
            int p = atomicAdd(&nk, 1);
            klist[p] = (unsigned short)k;
            ksigs[p] = ksig[k];
        }
    }
    __syncthreads();
    int m = nk;

    // probe: one q per thread; LDS reads are wave-uniform broadcasts
    int q = blockIdx.x * 256 + tid;
    unsigned long long sv = qsig[q];
    for (int i = 0; i < m; ++i) {
        if (ksigs[i] == sv) {
            int k = klist[i];
            for (int b = 0; b < BATCH; ++b) {
                if (qh[b * SLEN + q] == kh[b * SLEN + k]) {
                    int p = atomicAdd(&np, 1);
                    if (p < PB_CAP)
                        pairs[p] = ((unsigned)b << 24) | ((unsigned)q & 4095) << 12 | (unsigned)k;
                }
            }
        }
    }
    __syncthreads();
    int n = np < PB_CAP ? np : PB_CAP;

    // exact top-k among this block's pairs (same (b,q) pairs all live here)
    for (int i = tid; i < n; i += 256) {
        unsigned u = pairs[i];
        int b = u >> 24, qq = (u >> 12) & 4095, k = u & 4095;
        const float* qr = qup + ((size_t)(b * SLEN + qq)) * DIM;
        float si = dot64(qr, kup + ((size_t)(b * SLEN + k)) * DIM);
        int rank = 0;
        for (int j = 0; j < n; ++j) {
            unsigned v = pairs[j];
            if ((v >> 12) == (u >> 12)) {                 // same (b, q)
                int kj = v & 4095;
                float sj = dot64(qr, kup + ((size_t)(b * SLEN + kj)) * DIM);
                rank += (sj > si) || (sj == si && kj < k);
            }
        }
        if (rank < KMAX)
            out[((size_t)(b * SLEN + qq)) * KMAX + rank] = k;
    }
}

extern "C" void kernel_launch(void* const* d_in, const int* in_sizes, int n_in,
                              void* d_out, int out_size, void* d_ws, size_t ws_size,
                              hipStream_t stream)
{
    const float* qup = (const float*)d_in[0];
    const float* kup = (const float*)d_in[1];
    const float* W   = (const float*)d_in[2];
    int* out = (int*)d_out;

    char* w = (char*)d_ws;
    unsigned long long* qsig = (unsigned long long*)(w);             // 32 KB
    unsigned long long* ksig = (unsigned long long*)(w + 32768);     // 32 KB
    unsigned char* qh   = (unsigned char*)(w + 65536);               // 16 KB
    unsigned char* kh   = (unsigned char*)(w + 81920);               // 16 KB
    unsigned char* ins  = (unsigned char*)(w + 98304);               // 4 KB

    k_phase1<<<(2 * BATCH * SLEN * 8) / 256, 256, 0, stream>>>(
        qup, kup, W, qh, kh, qsig, ksig, ins, out);
    k_match<<<SLEN / 256, 256, 0, stream>>>(
        qup, kup, qsig, ksig, qh, kh, ins, out);
}

// Round 5
// 15.806 us; speedup vs baseline: 1.8314x; 1.5243x over previous
//
#include <hip/hip_runtime.h>
#include <stdint.h>

#define SLEN   4096
#define BATCH  4
#define DIM    64
#define HPROJ  16
#define KMAX   64

#define KL_CAP 4096      // exact upper bound on inserted keys
#define PB_CAP 1024      // per-block pair cap (expected ~0 pairs per block)

// ---------------- K1: per-token hash/signature + inserted bitmask + out init ----------------
// 8 threads per token (2 LSH projections each), shuffle-reduced. Core validated R1-R4.
__global__ void __launch_bounds__(256) k_phase1(
    const float* __restrict__ qup, const float* __restrict__ kup,
    const float* __restrict__ W,
    unsigned char* __restrict__ qh, unsigned char* __restrict__ kh,
    unsigned long long* __restrict__ qsig, unsigned long long* __restrict__ ksig,
    unsigned char* __restrict__ insmask,     // 512 B: bit s = inserted[s]
    int* __restrict__ out)
{
    __shared__ float Ws[DIM * HPROJ];
    for (int i = threadIdx.x; i < DIM * HPROJ; i += 256) Ws[i] = W[i];
    __syncthreads();

    int gid = blockIdx.x * 256 + threadIdx.x;          // 0 .. 262143

    // -1 output init: one int4 per thread covers all BATCH*SLEN*KMAX ints
    ((int4*)out)[gid] = make_int4(-1, -1, -1, -1);

    int token  = gid >> 3;                             // 0 .. 32767
    int hg     = gid & 7;                              // projection group
    int tensor = token >> 14;                          // 0 = query, 1 = key  (B*S = 16384)
    int rem    = token & (BATCH * SLEN - 1);
    int b      = rem >> 12;
    int s      = rem & (SLEN - 1);

    const float* x = (tensor ? kup : qup) + (size_t)rem * DIM;

    float4 xv[DIM / 4];
#pragma unroll
    for (int dv = 0; dv < DIM / 4; ++dv)
        xv[dv] = ((const float4*)x)[dv];

    int h0 = hg * 2;
    float p0 = 0.0f, p1 = 0.0f;
#pragma unroll
    for (int dv = 0; dv < DIM / 4; ++dv) {
        float4 v = xv[dv];
        int d = dv * 4;
        p0 = fmaf(v.x, Ws[(d + 0) * HPROJ + h0], p0);
        p0 = fmaf(v.y, Ws[(d + 1) * HPROJ + h0], p0);
        p0 = fmaf(v.z, Ws[(d + 2) * HPROJ + h0], p0);
        p0 = fmaf(v.w, Ws[(d + 3) * HPROJ + h0], p0);
        p1 = fmaf(v.x, Ws[(d + 0) * HPROJ + h0 + 1], p1);
        p1 = fmaf(v.y, Ws[(d + 1) * HPROJ + h0 + 1], p1);
        p1 = fmaf(v.z, Ws[(d + 2) * HPROJ + h0 + 1], p1);
        p1 = fmaf(v.w, Ws[(d + 3) * HPROJ + h0 + 1], p1);
    }
    // floor(p/4): /4 exact in fp32
    int acc = (int)floorf(p0 * 0.25f) + (int)floorf(p1 * 0.25f);
    acc += __shfl_xor(acc, 1);
    acc += __shfl_xor(acc, 2);
    acc += __shfl_xor(acc, 4);

    if (hg == 0) {
        unsigned char hash = (unsigned char)(acc & 63);   // Python mod 64
        if (!tensor) qh[rem] = hash; else kh[rem] = hash;

        if (b == BATCH - 1) {
            unsigned long long bits = 0ull;
#pragma unroll
            for (int dv = 0; dv < DIM / 4; ++dv) {
                float4 v = xv[dv];
                int d = dv * 4;
                if (v.x > 0.0f) bits |= (1ull << (d + 0));
                if (v.y > 0.0f) bits |= (1ull << (d + 1));
                if (v.z > 0.0f) bits |= (1ull << (d + 2));
                if (v.w > 0.0f) bits |= (1ull << (d + 3));
            }
            if (!tensor) qsig[s] = bits; else ksig[s] = bits;
        }
    }

    // Wu-Manber filter, wave-parallel: region (tensor==1, b==0) is wave-uniform
    // (a wave spans 8 aligned tokens). All 8 lanes of a token compute ins;
    // ballot; lane 0 packs 8 token-bits into one byte -> single writer, no init.
    if (tensor == 1 && b == 0) {
        float4 q0 = ((const float4*)(qup + (size_t)s * DIM))[0];
        float4 q1 = ((const float4*)(qup + (size_t)s * DIM))[1];
        bool ins = ((q0.x > 0.0f) == (xv[0].x > 0.0f)) &
                   ((q0.y > 0.0f) == (xv[0].y > 0.0f)) &
                   ((q0.z > 0.0f) == (xv[0].z > 0.0f)) &
                   ((q0.w > 0.0f) == (xv[0].w > 0.0f)) &
                   ((q1.x > 0.0f) == (xv[1].x > 0.0f)) &
                   ((q1.y > 0.0f) == (xv[1].y > 0.0f));
        unsigned long long bal = __ballot((int)ins);
        if ((threadIdx.x & 63) == 0) {
            unsigned byte = 0;
#pragma unroll
            for (int j = 0; j < 8; ++j)
                byte |= (unsigned)((bal >> (8 * j)) & 1ull) << j;
            insmask[s >> 3] = (unsigned char)byte;       // s is lane0's s here
        }
    }
}

// ---------------- K2: bitmask compact + parallel sig gather + probe + local top-k ----------------
__device__ inline float dot64(const float* a, const float* b)
{
    float s = 0.0f;
#pragma unroll
    for (int d = 0; d < DIM; ++d) s = fmaf(a[d], b[d], s);
    return s;
}

__global__ void __launch_bounds__(64) k_probe(
    const float* __restrict__ qup, const float* __restrict__ kup,
    const unsigned long long* __restrict__ qsig,
    const unsigned long long* __restrict__ ksig,
    const unsigned char* __restrict__ qh, const unsigned char* __restrict__ kh,
    const unsigned long long* __restrict__ insmask,   // 64 words
    int* __restrict__ out)
{
    __shared__ unsigned long long ks[KL_CAP];
    __shared__ unsigned short     kl[KL_CAP];
    __shared__ unsigned int       pairs[PB_CAP];
    __shared__ int nk, np;

    int tid = threadIdx.x;                  // 0..63
    if (tid == 0) { nk = 0; np = 0; }
    __syncthreads();

    // compact inserted keys: one bitmask word per thread, fully parallel
    unsigned long long mw = insmask[tid];
    int cnt = __popcll(mw);
    int pos = cnt ? atomicAdd(&nk, cnt) : 0;
    int base = tid * 64;
    while (mw) {
        int bit = __ffsll((long long)mw) - 1;
        mw &= mw - 1;
        kl[pos++] = (unsigned short)(base + bit);
    }
    __syncthreads();
    int m = nk;

    // gather signatures: one parallel global-load round per 64 keys (no serial chain)
    for (int i = tid; i < m; i += 64) ks[i] = ksig[kl[i]];

    // q-side state (overlaps with gather)
    int q = blockIdx.x * 64 + tid;
    unsigned long long sv = qsig[q];
    unsigned char q0 = qh[q];
    unsigned char q1 = qh[SLEN + q];
    unsigned char q2 = qh[2 * SLEN + q];
    unsigned char q3 = qh[3 * SLEN + q];
    __syncthreads();

    // probe: LDS broadcast reads, unrolled x4 so ds_reads batch
    int i = 0;
    for (; i + 4 <= m; i += 4) {
        unsigned long long a = ks[i], b2 = ks[i + 1], c = ks[i + 2], d = ks[i + 3];
#pragma unroll
        for (int t = 0; t < 4; ++t) {
            unsigned long long sk = (t == 0) ? a : (t == 1) ? b2 : (t == 2) ? c : d;
            if (sk == sv) {
                int k = kl[i + t];
                unsigned char kh0 = kh[k], kh1 = kh[SLEN + k],
                              kh2 = kh[2 * SLEN + k], kh3 = kh[3 * SLEN + k];
                unsigned qk = ((unsigned)(q & 4095) << 12) | (unsigned)k;
                if (q0 == kh0) { int p = atomicAdd(&np, 1); if (p < PB_CAP) pairs[p] = (0u << 24) | qk; }
                if (q1 == kh1) { int p = atomicAdd(&np, 1); if (p < PB_CAP) pairs[p] = (1u << 24) | qk; }
                if (q2 == kh2) { int p = atomicAdd(&np, 1); if (p < PB_CAP) pairs[p] = (2u << 24) | qk; }
                if (q3 == kh3) { int p = atomicAdd(&np, 1); if (p < PB_CAP) pairs[p] = (3u << 24) | qk; }
            }
        }
    }
    for (; i < m; ++i) {
        if (ks[i] == sv) {
            int k = kl[i];
            unsigned char kh0 = kh[k], kh1 = kh[SLEN + k],
                          kh2 = kh[2 * SLEN + k], kh3 = kh[3 * SLEN + k];
            unsigned qk = ((unsigned)(q & 4095) << 12) | (unsigned)k;
            if (q0 == kh0) { int p = atomicAdd(&np, 1); if (p < PB_CAP) pairs[p] = (0u << 24) | qk; }
            if (q1 == kh1) { int p = atomicAdd(&np, 1); if (p < PB_CAP) pairs[p] = (1u << 24) | qk; }
            if (q2 == kh2) { int p = atomicAdd(&np, 1); if (p < PB_CAP) pairs[p] = (2u << 24) | qk; }
            if (q3 == kh3) { int p = atomicAdd(&np, 1); if (p < PB_CAP) pairs[p] = (3u << 24) | qk; }
        }
    }
    __syncthreads();
    int n = np < PB_CAP ? np : PB_CAP;

    // exact top-k among this block's pairs (all pairs of a q live in its block);
    // rank semantics identical to lax.top_k (desc, stable by index) — validated R2-R4
    for (int idx = tid; idx < n; idx += 64) {
        unsigned u = pairs[idx];
        int b = u >> 24, qq = (u >> 12) & 4095, k = u & 4095;
        const float* qr = qup + ((size_t)(b * SLEN + qq)) * DIM;
        float si = dot64(qr, kup + ((size_t)(b * SLEN + k)) * DIM);
        int rank = 0;
        for (int j = 0; j < n; ++j) {
            unsigned v = pairs[j];
            if ((v >> 12) == (u >> 12)) {                 // same (b, q)
                int kj = v & 4095;
                float sj = dot64(qr, kup + ((size_t)(b * SLEN + kj)) * DIM);
                rank += (sj > si) || (sj == si && kj < k);
            }
        }
        if (rank < KMAX)
            out[((size_t)(b * SLEN + qq)) * KMAX + rank] = k;
    }
}

extern "C" void kernel_launch(void* const* d_in, const int* in_sizes, int n_in,
                              void* d_out, int out_size, void* d_ws, size_t ws_size,
                              hipStream_t stream)
{
    const float* qup = (const float*)d_in[0];
    const float* kup = (const float*)d_in[1];
    const float* W   = (const float*)d_in[2];
    int* out = (int*)d_out;

    char* w = (char*)d_ws;
    unsigned long long* qsig = (unsigned long long*)(w);             // 32 KB
    unsigned long long* ksig = (unsigned long long*)(w + 32768);     // 32 KB
    unsigned char* qh   = (unsigned char*)(w + 65536);               // 16 KB
    unsigned char* kh   = (unsigned char*)(w + 81920);               // 16 KB
    unsigned char* ins  = (unsigned char*)(w + 98304);               // 512 B bitmask

    k_phase1<<<(2 * BATCH * SLEN * 8) / 256, 256, 0, stream>>>(
        qup, kup, W, qh, kh, qsig, ksig, ins, out);
    k_probe<<<SLEN / 64, 64, 0, stream>>>(
        qup, kup, qsig, ksig, qh, kh, (const unsigned long long*)ins, out);
}